// Round 9
// baseline (251.935 us; speedup 1.0000x reference)
//
#include <hip/hip_runtime.h>

// SelfAttention: GN -> 1x1 QKV -> softmax attention (HW=1024) -> 1x1 proj + residual
// B=16, C=512, HW=1024, GROUPS=32, EPS=1e-5, scale=C^-0.5
//
// Round 17: 1-barrier K-steps on the R13/R15 best-known-good base (225us; QKV 47us,
// MfmaUtil 20%). R16 proved dispatch gaps ~0 -> all time is inside kernels. Audit
// found R13's intra-step barrier (between phase0/phase1, SAME LDS buffer both sides)
// protects nothing but walls off read/MFMA overlap and costs a rendezvous; R14's
// regression was its __syncthreads (vmcnt-0 drain) per step, not geometry. This round:
// per K32-step = [stage(s+2) 3 instr] [8 ds_read] [16 MFMA, setprio] [vmcnt(3)]
// [s_barrier]. 4-slot LDS: read slot s&3, landing (s+1)&3, staging (s+2)&3 - all
// distinct mod 4 with one barrier/step -> safe. Counted ledger unchanged (vmcnt(3)
// proves s+1 landed; drain only at tile end). Everything else identical to R16:
// persistent strip-streaming, 256x128 tile, 8 waves of 64x64, zero-conflict chunk
// swizzle, MODE 3 scores epilogue exp(alpha*s-6)+atomic row sums, MODE 4 PV scale,
// merged prep, 5 dispatches.
// Layouts (all [free][K]):
//   xnT [b][hw][c], qkT [b][hw][q|k], v [b][c][hw], S/P' [b][i][j], aoutT [b][hw][c]

typedef _Float16 f16;
typedef _Float16 f16x8 __attribute__((ext_vector_type(8)));
typedef _Float16 f16x4 __attribute__((ext_vector_type(4)));
typedef float fx4 __attribute__((ext_vector_type(4)));

__device__ __forceinline__ void gload16(const f16* g, f16* l) {
    __builtin_amdgcn_global_load_lds((const __attribute__((address_space(1))) void*)g,
                                     (__attribute__((address_space(3))) void*)l, 16, 0, 0);
}

// ---------------- prep: wconv(qkv), wconv(proj)+Dsum zero, GroupNorm — one dispatch ---------
// blocks [0,768): w_qkv fp32->f16 (196608 float4 chunks, exactly 768*256)
// blocks [768,1024): w_proj fp32->f16 (65536 chunks, exactly 256*256); + zero Dsum (16K f32)
// blocks [1024,1536): GroupNorm, blk-1024 = b*32+g
__global__ __launch_bounds__(256)
void prep_kernel(const float* __restrict__ w_qkv, f16* __restrict__ wqkvh,
                 const float* __restrict__ w_proj, f16* __restrict__ wprjh,
                 float* __restrict__ Dsum,
                 const float* __restrict__ x, const float* __restrict__ gamma,
                 const float* __restrict__ beta, f16* __restrict__ xnT)
{
    const int bx = blockIdx.x;
    const int tid = threadIdx.x;

    if (bx < 768) {                       // ---- w_qkv convert ----
        int i = bx * 256 + tid;
        float4 v = *(const float4*)(w_qkv + i * 4);
        f16x4 h;
        h[0] = (f16)v.x; h[1] = (f16)v.y; h[2] = (f16)v.z; h[3] = (f16)v.w;
        *(f16x4*)(wqkvh + i * 4) = h;
        return;
    }
    if (bx < 1024) {                      // ---- w_proj convert + Dsum zero ----
        int i = (bx - 768) * 256 + tid;
        float4 v = *(const float4*)(w_proj + i * 4);
        f16x4 h;
        h[0] = (f16)v.x; h[1] = (f16)v.y; h[2] = (f16)v.z; h[3] = (f16)v.w;
        *(f16x4*)(wprjh + i * 4) = h;
        if (tid < 64) Dsum[(bx - 768) * 64 + tid] = 0.f;
        return;
    }

    // ---- GroupNorm ----
    __shared__ float red[256], red2[256];
    __shared__ float mu_s, rs_s;
    __shared__ __align__(16) f16 T[16][1040];  // [ch][hw], padded
    const int blk = bx - 1024;                 // b*32 + g
    const int b = blk >> 5, g = blk & 31;
    const long base = (long)blk * 16384;       // 16 ch * 1024 hw
    const float4* xv = (const float4*)(x + base);

    float4 xr[16];
    float s = 0.f, s2 = 0.f;
#pragma unroll
    for (int i = 0; i < 16; i++) {
        float4 v = xv[tid + i * 256];
        xr[i] = v;
        s  += v.x + v.y + v.z + v.w;
        s2 += v.x * v.x + v.y * v.y + v.z * v.z + v.w * v.w;
    }
    red[tid] = s; red2[tid] = s2;
    __syncthreads();
    for (int off = 128; off > 0; off >>= 1) {
        if (tid < off) { red[tid] += red[tid + off]; red2[tid] += red2[tid + off]; }
        __syncthreads();
    }
    if (tid == 0) {
        float mu = red[0] * (1.f / 16384.f);
        float var = red2[0] * (1.f / 16384.f) - mu * mu;
        mu_s = mu;
        rs_s = rsqrtf(var + 1e-5f);
    }
    __syncthreads();
    const float mu = mu_s, rs = rs_s;

#pragma unroll
    for (int i = 0; i < 16; i++) {
        float gm = gamma[g * 16 + i] * rs;
        float bt = beta[g * 16 + i] - mu * gm;
        float4 v = xr[i];
        f16x4 o;
        o[0] = (f16)(v.x * gm + bt);
        o[1] = (f16)(v.y * gm + bt);
        o[2] = (f16)(v.z * gm + bt);
        o[3] = (f16)(v.w * gm + bt);
        *(f16x4*)&T[i][tid * 4] = o;
    }
    __syncthreads();
#pragma unroll
    for (int i = 0; i < 8; i++) {
        int idx = tid + i * 256;
        int hw = idx >> 1;
        int half8 = (idx & 1) * 8;
        f16x8 o;
#pragma unroll
        for (int j = 0; j < 8; j++) o[j] = T[half8 + j][hw];
        long dst = ((long)b * 1024 + hw) * 512 + g * 16 + half8;
        *(f16x8*)(xnT + dst) = o;
    }
}

// -------- persistent 256x128 MFMA GEMM, 8 waves of 64x64, 1-barrier counted pipeline --------
// A stored [M][K] f16 (lda), B stored [N][K] f16 (ldb); async staged via global_load_lds w16.
// Batch-folded tile space: id -> b = id/tpb, r = id%tpb, m0 = (r%nm)*256, n0 = (r/nm)*128.
// K staged in 32-wide steps H_s (s = 0..H-1, H = K/32), LDS slot = s&3.
// Per step: stage(s+2) -> 8 ds_read -> 16 MFMA (setprio) -> vmcnt(3) -> s_barrier.
// Slot safety (one barrier/step): readers hold slot s&3, landing (s+1)&3, staging
// (s+2)&3 - pairwise distinct mod 4. vmcnt(3) proves s+1 landed for this wave; the
// barrier extends it to all waves. Drain (vmcnt 0) only at s==H-2.
// MODE 1: QKV split (q,k -> qkT; v transposed -> C2p; bias[n]).
// MODE 2: fp32 out + bias[m] + resid.
// MODE 3: scores->P': f16 out = exp(alpha*acc - 6), row sums atomicAdd into Dsum[b*1024+row].
// MODE 4: PV: f16 out = acc * (1/Dsum[b*1024+row]).
template<int MODE>
__global__ __launch_bounds__(512, 2)
void pgemm_kernel(const f16* __restrict__ Ap, const f16* __restrict__ Bp,
                  void* __restrict__ Cp, f16* __restrict__ C2p,
                  const float* __restrict__ bias, const float* __restrict__ resid,
                  float* __restrict__ Dsum,
                  float alpha, int K, int lda, int ldb, int N,
                  int nm, int tpb, int nT,
                  long sAb, long sBb, long sCb)
{
    __shared__ __align__(16) f16 As[4][256 * 32];   // 64 KB (4 slots)
    __shared__ __align__(16) f16 Bs[4][128 * 32];   // 32 KB

    // XCD-bijective block remap: 256 blocks -> 8 XCDs x 32 contiguous ids
    const int blk = (blockIdx.x & 7) * 32 + (blockIdx.x >> 3);

    const int tid = threadIdx.x;
    const int wave = tid >> 6, lane = tid & 63;
    const int quad = lane >> 4, l15 = lane & 15;
    const int wm = (wave >> 1) * 64, wn = (wave & 1) * 64;
    // read-side chunk swizzle (HW-verified 0 conflicts since R9): chunk = quad ^ ((row>>1)&3)
    const int chunkoff = (quad ^ ((l15 >> 1) & 3)) * 8;

    // staging: per gload instr, lane -> local row rl = lane>>2 (16 rows), chunk = lane&3,
    // source column pre-swizzled to match read-side swizzle
    const int rl = lane >> 2;
    const int swzc = ((lane & 3) ^ ((rl >> 1) & 3)) * 8;
    const int RA = wave * 32;     // A: 256 rows / 8 waves, 2 instrs
    const int RB = wave * 16;     // B: 128 rows / 8 waves, 1 instr
    const int H = K >> 5;

    for (int id = blk; id < nT; id += 256) {
        const int b  = id / tpb, r = id % tpb;
        const int m0 = (r % nm) * 256, n0 = (r / nm) * 128;
        const f16* agA = Ap + (long)b * sAb + (long)(m0 + RA + rl) * lda + swzc;
        const f16* agB = Bp + (long)b * sBb + (long)(n0 + RB + rl) * ldb + swzc;

        // ---- prologue: stage H0 (slot 0) then H1 (slot 1); prove H0; barrier ----
        gload16(agA,                 &As[0][RA * 32]);
        gload16(agA + 16 * lda,      &As[0][(RA + 16) * 32]);
        gload16(agB,                 &Bs[0][RB * 32]);
        gload16(agA + 32,            &As[1][RA * 32]);
        gload16(agA + 16 * lda + 32, &As[1][(RA + 16) * 32]);
        gload16(agB + 32,            &Bs[1][RB * 32]);
        asm volatile("s_waitcnt vmcnt(3)" ::: "memory");
        __builtin_amdgcn_s_barrier();

        fx4 acc[4][4] = {};
        for (int s = 0; s < H; ++s) {
            const f16* Ab = &As[s & 3][0];
            const f16* Bb = &Bs[s & 3][0];
            const bool pre = (s + 2 < H);
            // ---- stage H_{s+2} into slot (s+2)&3 (3 instrs/wave) ----
            if (pre) {
                f16* dA = &As[(s + 2) & 3][0];
                gload16(agA + (long)(s + 2) * 32,            dA + RA * 32);
                gload16(agA + 16 * lda + (long)(s + 2) * 32, dA + (RA + 16) * 32);
                gload16(agB + (long)(s + 2) * 32, &Bs[(s + 2) & 3][RB * 32]);
            }
            // ---- all frags for this K32-step (8 ds_read_b128) ----
            f16x8 af[4], bf[4];
#pragma unroll
            for (int fm = 0; fm < 4; fm++)
                af[fm] = *(const f16x8*)&Ab[(wm + fm * 16 + l15) * 32 + chunkoff];
#pragma unroll
            for (int fn = 0; fn < 4; fn++)
                bf[fn] = *(const f16x8*)&Bb[(wn + fn * 16 + l15) * 32 + chunkoff];
            // ---- 16 MFMA ----
            __builtin_amdgcn_s_setprio(1);
#pragma unroll
            for (int fm = 0; fm < 4; fm++)
#pragma unroll
                for (int fn = 0; fn < 4; fn++)
                    acc[fm][fn] = __builtin_amdgcn_mfma_f32_16x16x32_f16(af[fm], bf[fn], acc[fm][fn], 0, 0, 0);
            __builtin_amdgcn_s_setprio(0);
            // ---- ledger: prove H_{s+1} landed (this wave), then rendezvous ----
            if (pre)               { asm volatile("s_waitcnt vmcnt(3)" ::: "memory"); }
            else if (s == H - 2)   { asm volatile("s_waitcnt vmcnt(0)" ::: "memory"); }
            __builtin_amdgcn_s_barrier();
        }

        // ---- epilogue: D[row = quad*4+rr][col = l15] per 16x16 tile ----
        if (MODE == 1 && n0 >= 1024) {
            // v-part: write transposed to v[b][c][hw], vectorized f16x4 along hw(=m)
#pragma unroll
            for (int tm = 0; tm < 4; tm++)
#pragma unroll
            for (int tn = 0; tn < 4; tn++) {
                int gc = n0 + wn + tn * 16 + l15;
                int gr0 = m0 + wm + tm * 16 + quad * 4;
                float bs = bias[gc];
                f16x4 o;
#pragma unroll
                for (int rr = 0; rr < 4; rr++) o[rr] = (f16)(acc[tm][tn][rr] + bs);
                *(f16x4*)(C2p + (long)b * 524288 + (long)(gc - 1024) * 1024 + gr0) = o;
            }
        } else if (MODE == 3) {
            // scores -> P' = exp(alpha*s - 6), f16; accumulate row sums into Dsum
#pragma unroll
            for (int tm = 0; tm < 4; tm++)
#pragma unroll
            for (int rr = 0; rr < 4; rr++) {
                const int gr = m0 + wm + tm * 16 + quad * 4 + rr;
                float part = 0.f;
#pragma unroll
                for (int tn = 0; tn < 4; tn++) {
                    int gc = n0 + wn + tn * 16 + l15;
                    float p = __expf(alpha * acc[tm][tn][rr] - 6.0f);
                    part += p;
                    ((f16*)Cp)[(long)b * sCb + (long)gr * N + gc] = (f16)p;
                }
                // sum over the 16 lanes (l15) of this quad: 4 tn x 16 lanes = 64 j-values
                part += __shfl_xor(part, 1, 64);
                part += __shfl_xor(part, 2, 64);
                part += __shfl_xor(part, 4, 64);
                part += __shfl_xor(part, 8, 64);
                if (l15 == 0) atomicAdd(Dsum + b * 1024 + gr, part);
            }
        } else if (MODE == 4) {
            // PV: scale accumulator by 1/rowsum
#pragma unroll
            for (int tm = 0; tm < 4; tm++)
#pragma unroll
            for (int rr = 0; rr < 4; rr++) {
                const int gr = m0 + wm + tm * 16 + quad * 4 + rr;
                const float rs = 1.0f / Dsum[b * 1024 + gr];
#pragma unroll
                for (int tn = 0; tn < 4; tn++) {
                    int gc = n0 + wn + tn * 16 + l15;
                    ((f16*)Cp)[(long)b * sCb + (long)gr * N + gc] = (f16)(acc[tm][tn][rr] * rs);
                }
            }
        } else {
#pragma unroll
            for (int tm = 0; tm < 4; tm++)
#pragma unroll
            for (int tn = 0; tn < 4; tn++) {
                int gc = n0 + wn + tn * 16 + l15;
#pragma unroll
                for (int rr = 0; rr < 4; rr++) {
                    int gr = m0 + wm + tm * 16 + quad * 4 + rr;
                    float v = acc[tm][tn][rr];
                    if (MODE == 1) {
                        v += bias[gc];
                        ((f16*)Cp)[(long)b * 1048576 + (long)gr * 1024 + gc] = (f16)v;
                    } else {  // MODE 2
                        v += bias[gr];
                        long idx = (long)b * sCb + (long)gr * N + gc;
                        v += resid[idx];
                        ((float*)Cp)[idx] = v;
                    }
                }
            }
        }
    }
}

extern "C" void kernel_launch(void* const* d_in, const int* in_sizes, int n_in,
                              void* d_out, int out_size, void* d_ws, size_t ws_size,
                              hipStream_t stream)
{
    const float* x      = (const float*)d_in[0];
    const float* gamma  = (const float*)d_in[1];
    const float* beta   = (const float*)d_in[2];
    const float* w_qkv  = (const float*)d_in[3];
    const float* b_qkv  = (const float*)d_in[4];
    const float* w_proj = (const float*)d_in[5];
    const float* b_proj = (const float*)d_in[6];
    float* out = (float*)d_out;

    char* ws = (char*)d_ws;
    f16* xnT   = (f16*)(ws);                 // 16 MB : [16][1024 hw][512 c]
    f16* qkT   = (f16*)(ws + (16L << 20));   // 32 MB : [16][1024 hw][1024 (q|k)]
    f16* vbuf  = (f16*)(ws + (48L << 20));   // 16 MB : [16][512 c][1024 hw]
    f16* S     = (f16*)(ws + (64L << 20));   // 32 MB : [16][1024 i][1024 j] (holds P')
    f16* aoutT = (f16*)(ws + (96L << 20));   // 16 MB : [16][1024 hw][512 c]
    float* Dsum = (float*)(ws + (112L << 20));            // 64 KB : [16][1024] row sums
    f16* wprjh  = (f16*)(ws + (112L << 20) + (1L << 16)); // 0.5 MB : dedicated (no alias)
    f16* wqkvh = S;                          // 1.5 MB; dead before scores writes S

    // 0) prep: w_qkv->f16, w_proj->f16, Dsum zero, GroupNorm — one dispatch
    prep_kernel<<<1536, 256, 0, stream>>>(w_qkv, wqkvh, w_proj, wprjh, Dsum,
                                          x, gamma, beta, xnT);

    // 1) QKV: C[m=hw][n=o] = xnT[hw][c] . w_qkv[o][c]; q,k -> qkT, v -> vbuf
    //    per-batch tiles: nm=4, nn=12, tpb=48, total 768 (T=3 per block)
    pgemm_kernel<1><<<256, 512, 0, stream>>>(
        xnT, wqkvh, qkT, vbuf, b_qkv, nullptr, nullptr, 1.0f,
        512, 512, 512, 1536,
        4, 48, 768,
        524288L, 0L, 0L);

    // 2) Scores + fused shifted-softmax numerator: P'[i][j] = exp(scale*q.k - 6),
    //    row sums -> Dsum. nm=4, nn=8, tpb=32, total 512 (T=2)
    pgemm_kernel<3><<<256, 512, 0, stream>>>(
        qkT, qkT + 512, S, nullptr, nullptr, nullptr, Dsum, 0.04419417382415922f,
        512, 1024, 1024, 1024,
        4, 32, 512,
        1048576L, 1048576L, 1048576L);

    // 3) PV + normalize: aoutT[i][c] = (P'[i][j] . v[c][j]) / Dsum[i]
    //    nm=4, nn=4, tpb=16, total 256 (T=1), K=1024
    pgemm_kernel<4><<<256, 512, 0, stream>>>(
        S, vbuf, aoutT, nullptr, nullptr, nullptr, Dsum, 1.0f,
        1024, 1024, 1024, 512,
        4, 16, 256,
        1048576L, 524288L, 524288L);

    // 4) Proj: out[o][hw] = w_proj[o][c] . aoutT[hw][c] + b_proj[o] + x
    //    nm=2, nn=8, tpb=16, total 256 (T=1)
    pgemm_kernel<2><<<256, 512, 0, stream>>>(
        wprjh, aoutT, out, nullptr, b_proj, x, nullptr, 1.0f,
        512, 512, 512, 1024,
        2, 16, 256,
        0L, 524288L, 524288L);
}

// Round 10
// 213.799 us; speedup vs baseline: 1.1784x; 1.1784x over previous
//
#include <hip/hip_runtime.h>

// SelfAttention: GN -> 1x1 QKV -> softmax attention (HW=1024) -> 1x1 proj + residual
// B=16, C=512, HW=1024, GROUPS=32, EPS=1e-5, scale=C^-0.5
//
// Round 18: REVERT R17 (1-barrier loop regressed 47->57: barrier placement, not count,
// was load-bearing) back to the R15/R16 2-phase core, + LDS-bounce epilogue for MODE 1.
// Write-path theory (explains all 9 rounds): epilogues store C 2B/lane -> each store
// instr = 4x32B segments scattered 2KB apart; ~64 scalar stores/tile all count in
// vmcnt, and the next tile's vmcnt(3) ledger DRAINS them on the critical path. All
// pipes <21%, schedules null, hbm pinned ~1.6TB/s = sector-inefficient write drain.
// Fix here: after the K-loop the 96KB LDS is dead; acc -> LDS (f16, padded strides
// 136 q/k, 264 v -> <=4-way conflicts), barrier, then 8 coalesced f16x8 stores/thread
// (256B segments, 1KB/instr/wave) replace 64 scattered 2B stores. MODE 1 (QKV, 48MB
// writes, the measured stage) only this round; 2/3/4 inherit if proven.
// Core = R16: persistent strips, 256x128 tile, 8 waves 64x64, 2-phase K32 steps,
// counted vmcnt(3) ledger, zero-conflict chunk swizzle, XCD batch pinning, merged prep.
// Layouts (all [free][K]):
//   xnT [b][hw][c], qkT [b][hw][q|k], v [b][c][hw], S/P' [b][i][j], aoutT [b][hw][c]

typedef _Float16 f16;
typedef _Float16 f16x8 __attribute__((ext_vector_type(8)));
typedef _Float16 f16x4 __attribute__((ext_vector_type(4)));
typedef float fx4 __attribute__((ext_vector_type(4)));

__device__ __forceinline__ void gload16(const f16* g, f16* l) {
    __builtin_amdgcn_global_load_lds((const __attribute__((address_space(1))) void*)g,
                                     (__attribute__((address_space(3))) void*)l, 16, 0, 0);
}

// ---------------- prep: wconv(qkv), wconv(proj)+Dsum zero, GroupNorm — one dispatch ---------
__global__ __launch_bounds__(256)
void prep_kernel(const float* __restrict__ w_qkv, f16* __restrict__ wqkvh,
                 const float* __restrict__ w_proj, f16* __restrict__ wprjh,
                 float* __restrict__ Dsum,
                 const float* __restrict__ x, const float* __restrict__ gamma,
                 const float* __restrict__ beta, f16* __restrict__ xnT)
{
    const int bx = blockIdx.x;
    const int tid = threadIdx.x;

    if (bx < 768) {                       // ---- w_qkv convert ----
        int i = bx * 256 + tid;
        float4 v = *(const float4*)(w_qkv + i * 4);
        f16x4 h;
        h[0] = (f16)v.x; h[1] = (f16)v.y; h[2] = (f16)v.z; h[3] = (f16)v.w;
        *(f16x4*)(wqkvh + i * 4) = h;
        return;
    }
    if (bx < 1024) {                      // ---- w_proj convert + Dsum zero ----
        int i = (bx - 768) * 256 + tid;
        float4 v = *(const float4*)(w_proj + i * 4);
        f16x4 h;
        h[0] = (f16)v.x; h[1] = (f16)v.y; h[2] = (f16)v.z; h[3] = (f16)v.w;
        *(f16x4*)(wprjh + i * 4) = h;
        if (tid < 64) Dsum[(bx - 768) * 64 + tid] = 0.f;
        return;
    }

    // ---- GroupNorm ----
    __shared__ float red[256], red2[256];
    __shared__ float mu_s, rs_s;
    __shared__ __align__(16) f16 T[16][1040];  // [ch][hw], padded
    const int blk = bx - 1024;                 // b*32 + g
    const int b = blk >> 5, g = blk & 31;
    const long base = (long)blk * 16384;       // 16 ch * 1024 hw
    const float4* xv = (const float4*)(x + base);

    float4 xr[16];
    float s = 0.f, s2 = 0.f;
#pragma unroll
    for (int i = 0; i < 16; i++) {
        float4 v = xv[tid + i * 256];
        xr[i] = v;
        s  += v.x + v.y + v.z + v.w;
        s2 += v.x * v.x + v.y * v.y + v.z * v.z + v.w * v.w;
    }
    red[tid] = s; red2[tid] = s2;
    __syncthreads();
    for (int off = 128; off > 0; off >>= 1) {
        if (tid < off) { red[tid] += red[tid + off]; red2[tid] += red2[tid + off]; }
        __syncthreads();
    }
    if (tid == 0) {
        float mu = red[0] * (1.f / 16384.f);
        float var = red2[0] * (1.f / 16384.f) - mu * mu;
        mu_s = mu;
        rs_s = rsqrtf(var + 1e-5f);
    }
    __syncthreads();
    const float mu = mu_s, rs = rs_s;

#pragma unroll
    for (int i = 0; i < 16; i++) {
        float gm = gamma[g * 16 + i] * rs;
        float bt = beta[g * 16 + i] - mu * gm;
        float4 v = xr[i];
        f16x4 o;
        o[0] = (f16)(v.x * gm + bt);
        o[1] = (f16)(v.y * gm + bt);
        o[2] = (f16)(v.z * gm + bt);
        o[3] = (f16)(v.w * gm + bt);
        *(f16x4*)&T[i][tid * 4] = o;
    }
    __syncthreads();
#pragma unroll
    for (int i = 0; i < 8; i++) {
        int idx = tid + i * 256;
        int hw = idx >> 1;
        int half8 = (idx & 1) * 8;
        f16x8 o;
#pragma unroll
        for (int j = 0; j < 8; j++) o[j] = T[half8 + j][hw];
        long dst = ((long)b * 1024 + hw) * 512 + g * 16 + half8;
        *(f16x8*)(xnT + dst) = o;
    }
}

// -------- persistent 256x128 MFMA GEMM, 8 waves of 64x64, fine-phase streamed pipeline -------
// Carved smem: As(s) = smem + s*8192 (4 x 16KB), Bs(s) = smem + 32768 + s*4096 (4 x 8KB).
// MODE 1 epilogue: LDS-bounce (Cb overlays smem; K-loop done -> safe; barriers fence reuse).
// MODE 3: scores->P' = exp(alpha*acc - 6) + atomic row sums. MODE 4: PV * 1/Dsum.
// MODE 2: fp32 out + bias[m] + resid.
template<int MODE>
__global__ __launch_bounds__(512, 2)
void pgemm_kernel(const f16* __restrict__ Ap, const f16* __restrict__ Bp,
                  void* __restrict__ Cp, f16* __restrict__ C2p,
                  const float* __restrict__ bias, const float* __restrict__ resid,
                  float* __restrict__ Dsum,
                  float alpha, int K, int lda, int ldb, int N,
                  int nm, int tpb, int nT,
                  long sAb, long sBb, long sCb)
{
    __shared__ __align__(16) f16 smem[49152];   // 96 KB
#define AS(s) (smem + (s) * 8192)
#define BS(s) (smem + 32768 + (s) * 4096)

    // XCD-bijective block remap: 256 blocks -> 8 XCDs x 32 contiguous ids
    const int blk = (blockIdx.x & 7) * 32 + (blockIdx.x >> 3);

    const int tid = threadIdx.x;
    const int wave = tid >> 6, lane = tid & 63;
    const int quad = lane >> 4, l15 = lane & 15;
    const int wm = (wave >> 1) * 64, wn = (wave & 1) * 64;
    // read-side chunk swizzle (HW-verified 0 conflicts since R9): chunk = quad ^ ((row>>1)&3)
    const int chunkoff = (quad ^ ((l15 >> 1) & 3)) * 8;

    // staging: per gload instr, lane -> local row rl = lane>>2 (16 rows), chunk = lane&3,
    // source column pre-swizzled to match read-side swizzle
    const int rl = lane >> 2;
    const int swzc = ((lane & 3) ^ ((rl >> 1) & 3)) * 8;
    const int RA = wave * 32;     // A: 256 rows / 8 waves, 2 instrs
    const int RB = wave * 16;     // B: 128 rows / 8 waves, 1 instr
    const int H = K >> 5;

    for (int id = blk; id < nT; id += 256) {
        const int b  = id / tpb, r = id % tpb;
        const int m0 = (r % nm) * 256, n0 = (r / nm) * 128;
        const f16* agA = Ap + (long)b * sAb + (long)(m0 + RA + rl) * lda + swzc;
        const f16* agB = Bp + (long)b * sBb + (long)(n0 + RB + rl) * ldb + swzc;

        // ---- prologue: stage H0 then H1; prove H0 before entering loop ----
        gload16(agA,                 AS(0) + RA * 32);
        gload16(agA + 16 * lda,      AS(0) + (RA + 16) * 32);
        gload16(agB,                 BS(0) + RB * 32);
        gload16(agA + 32,            AS(1) + RA * 32);
        gload16(agA + 16 * lda + 32, AS(1) + (RA + 16) * 32);
        gload16(agB + 32,            BS(1) + RB * 32);
        asm volatile("s_waitcnt vmcnt(3)" ::: "memory");
        __builtin_amdgcn_s_barrier();

        fx4 acc[4][4] = {};
        for (int s = 0; s < H; ++s) {
            const f16* Ab = AS(s & 3);
            const f16* Bb = BS(s & 3);
            const bool pre = (s + 2 < H);
            // ---- phase 0: A frags + B lo-half frags; stage A of H_{s+2} ----
            f16x8 af[4], bf[4];
#pragma unroll
            for (int fm = 0; fm < 4; fm++)
                af[fm] = *(const f16x8*)&Ab[(wm + fm * 16 + l15) * 32 + chunkoff];
#pragma unroll
            for (int fn = 0; fn < 2; fn++)
                bf[fn] = *(const f16x8*)&Bb[(wn + fn * 16 + l15) * 32 + chunkoff];
            if (pre) {
                f16* d = AS((s + 2) & 3);
                gload16(agA + (long)(s + 2) * 32,            d + RA * 32);
                gload16(agA + 16 * lda + (long)(s + 2) * 32, d + (RA + 16) * 32);
            }
            __builtin_amdgcn_s_barrier();
            __builtin_amdgcn_s_setprio(1);
#pragma unroll
            for (int fm = 0; fm < 4; fm++)
#pragma unroll
                for (int fn = 0; fn < 2; fn++)
                    acc[fm][fn] = __builtin_amdgcn_mfma_f32_16x16x32_f16(af[fm], bf[fn], acc[fm][fn], 0, 0, 0);
            __builtin_amdgcn_s_setprio(0);
            __builtin_amdgcn_s_barrier();
            // ---- phase 1: B hi-half frags; stage B of H_{s+2}; prove H_{s+1} ----
#pragma unroll
            for (int fn = 2; fn < 4; fn++)
                bf[fn] = *(const f16x8*)&Bb[(wn + fn * 16 + l15) * 32 + chunkoff];
            if (pre)
                gload16(agB + (long)(s + 2) * 32, BS((s + 2) & 3) + RB * 32);
            __builtin_amdgcn_s_setprio(1);
#pragma unroll
            for (int fm = 0; fm < 4; fm++)
#pragma unroll
                for (int fn = 2; fn < 4; fn++)
                    acc[fm][fn] = __builtin_amdgcn_mfma_f32_16x16x32_f16(af[fm], bf[fn], acc[fm][fn], 0, 0, 0);
            __builtin_amdgcn_s_setprio(0);
            if (pre)               { asm volatile("s_waitcnt vmcnt(3)" ::: "memory"); }
            else if (s == H - 2)   { asm volatile("s_waitcnt vmcnt(0)" ::: "memory"); }
            __builtin_amdgcn_s_barrier();
        }

        // ---- epilogue: D[row = quad*4+rr][col = l15] per 16x16 tile ----
        if (MODE == 1) {
            // LDS-bounce: acc -> smem (f16, padded) -> coalesced f16x8 global stores.
            // K-loop's final barrier passed: all waves done with As/Bs -> smem reusable.
            if (n0 < 1024) {
                // q/k part -> qkT[b][m][n], rows m, 128 f16/row. Cb[256][136] (69.6KB)
                const int LDC = 136;
#pragma unroll
                for (int tm = 0; tm < 4; tm++)
#pragma unroll
                for (int tn = 0; tn < 4; tn++) {
                    float bs = bias[n0 + wn + tn * 16 + l15];
#pragma unroll
                    for (int rr = 0; rr < 4; rr++)
                        smem[(wm + tm * 16 + quad * 4 + rr) * LDC + wn + tn * 16 + l15] =
                            (f16)(acc[tm][tn][rr] + bs);
                }
                __builtin_amdgcn_s_barrier();
                f16* outp = (f16*)Cp + (long)b * 1048576;
#pragma unroll
                for (int i = 0; i < 8; i++) {
                    int idx = tid + i * 512;
                    int row = idx >> 4, seg = idx & 15;
                    f16x8 val = *(const f16x8*)&smem[row * LDC + seg * 8];
                    *(f16x8*)(outp + (long)(m0 + row) * 1024 + n0 + seg * 8) = val;
                }
            } else {
                // v part -> vbuf[b][c][hw], rows c=128, 256 f16/row. Cb[128][264] (67.6KB)
                const int LDV = 264;
#pragma unroll
                for (int tm = 0; tm < 4; tm++)
#pragma unroll
                for (int tn = 0; tn < 4; tn++) {
                    int gcl = wn + tn * 16 + l15;
                    float bs = bias[n0 + gcl];
                    f16x4 o;
#pragma unroll
                    for (int rr = 0; rr < 4; rr++) o[rr] = (f16)(acc[tm][tn][rr] + bs);
                    *(f16x4*)&smem[gcl * LDV + wm + tm * 16 + quad * 4] = o;
                }
                __builtin_amdgcn_s_barrier();
                f16* outp = C2p + (long)b * 524288;
#pragma unroll
                for (int i = 0; i < 8; i++) {
                    int idx = tid + i * 512;
                    int row = idx >> 5, seg = idx & 31;
                    f16x8 val = *(const f16x8*)&smem[row * LDV + seg * 8];
                    *(f16x8*)(outp + (long)(n0 - 1024 + row) * 1024 + m0 + seg * 8) = val;
                }
            }
            // fence: all waves done READING smem before next tile's prologue stages into it
            __builtin_amdgcn_s_barrier();
        } else if (MODE == 3) {
            // scores -> P' = exp(alpha*s - 6), f16; accumulate row sums into Dsum
#pragma unroll
            for (int tm = 0; tm < 4; tm++)
#pragma unroll
            for (int rr = 0; rr < 4; rr++) {
                const int gr = m0 + wm + tm * 16 + quad * 4 + rr;
                float part = 0.f;
#pragma unroll
                for (int tn = 0; tn < 4; tn++) {
                    int gc = n0 + wn + tn * 16 + l15;
                    float p = __expf(alpha * acc[tm][tn][rr] - 6.0f);
                    part += p;
                    ((f16*)Cp)[(long)b * sCb + (long)gr * N + gc] = (f16)p;
                }
                part += __shfl_xor(part, 1, 64);
                part += __shfl_xor(part, 2, 64);
                part += __shfl_xor(part, 4, 64);
                part += __shfl_xor(part, 8, 64);
                if (l15 == 0) atomicAdd(Dsum + b * 1024 + gr, part);
            }
        } else if (MODE == 4) {
            // PV: scale accumulator by 1/rowsum
#pragma unroll
            for (int tm = 0; tm < 4; tm++)
#pragma unroll
            for (int rr = 0; rr < 4; rr++) {
                const int gr = m0 + wm + tm * 16 + quad * 4 + rr;
                const float rs = 1.0f / Dsum[b * 1024 + gr];
#pragma unroll
                for (int tn = 0; tn < 4; tn++) {
                    int gc = n0 + wn + tn * 16 + l15;
                    ((f16*)Cp)[(long)b * sCb + (long)gr * N + gc] = (f16)(acc[tm][tn][rr] * rs);
                }
            }
        } else {  // MODE 2
#pragma unroll
            for (int tm = 0; tm < 4; tm++)
#pragma unroll
            for (int tn = 0; tn < 4; tn++) {
                int gc = n0 + wn + tn * 16 + l15;
#pragma unroll
                for (int rr = 0; rr < 4; rr++) {
                    int gr = m0 + wm + tm * 16 + quad * 4 + rr;
                    float v = acc[tm][tn][rr] + bias[gr];
                    long idx = (long)b * sCb + (long)gr * N + gc;
                    v += resid[idx];
                    ((float*)Cp)[idx] = v;
                }
            }
        }
    }
#undef AS
#undef BS
}

extern "C" void kernel_launch(void* const* d_in, const int* in_sizes, int n_in,
                              void* d_out, int out_size, void* d_ws, size_t ws_size,
                              hipStream_t stream)
{
    const float* x      = (const float*)d_in[0];
    const float* gamma  = (const float*)d_in[1];
    const float* beta   = (const float*)d_in[2];
    const float* w_qkv  = (const float*)d_in[3];
    const float* b_qkv  = (const float*)d_in[4];
    const float* w_proj = (const float*)d_in[5];
    const float* b_proj = (const float*)d_in[6];
    float* out = (float*)d_out;

    char* ws = (char*)d_ws;
    f16* xnT   = (f16*)(ws);                 // 16 MB : [16][1024 hw][512 c]
    f16* qkT   = (f16*)(ws + (16L << 20));   // 32 MB : [16][1024 hw][1024 (q|k)]
    f16* vbuf  = (f16*)(ws + (48L << 20));   // 16 MB : [16][512 c][1024 hw]
    f16* S     = (f16*)(ws + (64L << 20));   // 32 MB : [16][1024 i][1024 j] (holds P')
    f16* aoutT = (f16*)(ws + (96L << 20));   // 16 MB : [16][1024 hw][512 c]
    float* Dsum = (float*)(ws + (112L << 20));            // 64 KB : [16][1024] row sums
    f16* wprjh  = (f16*)(ws + (112L << 20) + (1L << 16)); // 0.5 MB : dedicated (no alias)
    f16* wqkvh = S;                          // 1.5 MB; dead before scores writes S

    // 0) prep: w_qkv->f16, w_proj->f16, Dsum zero, GroupNorm — one dispatch
    prep_kernel<<<1536, 256, 0, stream>>>(w_qkv, wqkvh, w_proj, wprjh, Dsum,
                                          x, gamma, beta, xnT);

    // 1) QKV: C[m=hw][n=o] = xnT[hw][c] . w_qkv[o][c]; q,k -> qkT, v -> vbuf
    //    per-batch tiles: nm=4, nn=12, tpb=48, total 768 (T=3 per block)
    pgemm_kernel<1><<<256, 512, 0, stream>>>(
        xnT, wqkvh, qkT, vbuf, b_qkv, nullptr, nullptr, 1.0f,
        512, 512, 512, 1536,
        4, 48, 768,
        524288L, 0L, 0L);

    // 2) Scores + fused shifted-softmax numerator: P'[i][j] = exp(scale*q.k - 6),
    //    row sums -> Dsum. nm=4, nn=8, tpb=32, total 512 (T=2)
    pgemm_kernel<3><<<256, 512, 0, stream>>>(
        qkT, qkT + 512, S, nullptr, nullptr, nullptr, Dsum, 0.04419417382415922f,
        512, 1024, 1024, 1024,
        4, 32, 512,
        1048576L, 1048576L, 1048576L);

    // 3) PV + normalize: aoutT[i][c] = (P'[i][j] . v[c][j]) / Dsum[i]
    //    nm=4, nn=4, tpb=16, total 256 (T=1), K=1024
    pgemm_kernel<4><<<256, 512, 0, stream>>>(
        S, vbuf, aoutT, nullptr, nullptr, nullptr, Dsum, 1.0f,
        1024, 1024, 1024, 512,
        4, 16, 256,
        1048576L, 524288L, 524288L);

    // 4) Proj: out[o][hw] = w_proj[o][c] . aoutT[hw][c] + b_proj[o] + x
    //    nm=2, nn=8, tpb=16, total 256 (T=1)
    pgemm_kernel<2><<<256, 512, 0, stream>>>(
        wprjh, aoutT, out, nullptr, b_proj, x, nullptr, 1.0f,
        512, 512, 512, 1024,
        2, 16, 256,
        0L, 524288L, 524288L);
}